// Round 8
// baseline (427.843 us; speedup 1.0000x reference)
//
#include <hip/hip_runtime.h>

typedef unsigned short u16;
typedef unsigned int u32;
typedef __attribute__((ext_vector_type(2))) u32 u32x2;
typedef __attribute__((ext_vector_type(4))) u32 u32x4;
typedef __attribute__((ext_vector_type(8))) short bf16x8;
typedef __attribute__((ext_vector_type(4))) float f32x4;

// round-to-nearest-even fp32 -> bf16 (scalar fallback)
__device__ __forceinline__ u16 f2bf(float f) {
  u32 b = __float_as_uint(f);
  b += 0x7fffu + ((b >> 16) & 1u);
  return (u16)(b >> 16);
}

// packed fp32x2 -> bf16x2
__device__ __forceinline__ u32 pk2bf(float a, float b) {
#if __has_builtin(__builtin_amdgcn_cvt_pk_bf16_f32)
  return __builtin_bit_cast(u32, __builtin_amdgcn_cvt_pk_bf16_f32(a, b));
#else
  return (u32)f2bf(a) | ((u32)f2bf(b) << 16);
#endif
}

// 2^x via native v_exp_f32 (NOTE: __exp2f is a reserved glibc symbol)
__device__ __forceinline__ float fexp2(float x) {
#if __has_builtin(__builtin_amdgcn_exp2f)
  return __builtin_amdgcn_exp2f(x);
#else
  return exp2f(x);
#endif
}

// async global->LDS, 16B/lane (GEMM cores only)
__device__ __forceinline__ void gload_lds16(const u16* g, u16* l) {
  __builtin_amdgcn_global_load_lds((const __attribute__((address_space(1))) void*)g,
                                   (__attribute__((address_space(3))) void*)l, 16, 0, 0);
}

// ---------------- fp32 -> bf16 convert, 8 elems/thread ----------------------
__global__ __launch_bounds__(256) void cvt_f32_bf16(const float* __restrict__ in,
                                                    u16* __restrict__ out) {
  long i = ((long)blockIdx.x * 256 + threadIdx.x) * 8;
  u32 u[8];
#pragma unroll
  for (int j = 0; j < 8; j++) {
    u32 b = __float_as_uint(in[i + j]);
    u[j] = (b + 0x7fffu + ((b >> 16) & 1u)) >> 16;
  }
  u32x4 o;
  o[0] = u[0] | (u[1] << 16);
  o[1] = u[2] | (u[3] << 16);
  o[2] = u[4] | (u[5] << 16);
  o[3] = u[6] | (u[7] << 16);
  *(u32x4*)(out + i) = o;
}

// ---------------- shared GEMM core: C[128x128] = A[128xK] * B[128xK]^T ------
__device__ __forceinline__ void gemm_core_128(const u16* __restrict__ A,
                                              const u16* __restrict__ B, int K,
                                              int m0, int n0, u16* As, u16* Bs,
                                              f32x4 acc[4][4]) {
  int t = threadIdx.x;
  int lane = t & 63, w = t >> 6;
  int quad = lane >> 4, l16 = lane & 15;
  int wm = (w >> 1) * 64, wn = (w & 1) * 64;
  int lr = lane >> 3, lc = lane & 7;
  int cg = lc ^ lr;
  int swz = l16 & 7;
  for (int k0 = 0; k0 < K; k0 += 64) {
#pragma unroll
    for (int i = 0; i < 4; i++) {
      int r0 = i * 32 + w * 8;
      gload_lds16(&A[(long)(m0 + r0 + lr) * K + k0 + cg * 8], &As[r0 * 64]);
      gload_lds16(&B[(long)(n0 + r0 + lr) * K + k0 + cg * 8], &Bs[r0 * 64]);
    }
    __syncthreads();
#pragma unroll
    for (int ks = 0; ks < 2; ks++) {
      bf16x8 a[4], b[4];
#pragma unroll
      for (int tm = 0; tm < 4; tm++)
        a[tm] = *(const bf16x8*)&As[(wm + tm * 16 + l16) * 64 + ((ks * 4 + quad) ^ swz) * 8];
#pragma unroll
      for (int tn = 0; tn < 4; tn++)
        b[tn] = *(const bf16x8*)&Bs[(wn + tn * 16 + l16) * 64 + ((ks * 4 + quad) ^ swz) * 8];
#pragma unroll
      for (int tm = 0; tm < 4; tm++)
#pragma unroll
        for (int tn = 0; tn < 4; tn++)
          acc[tm][tn] = __builtin_amdgcn_mfma_f32_16x16x32_bf16(a[tm], b[tn],
                                                                acc[tm][tn], 0, 0, 0);
    }
    __syncthreads();
  }
}

// ---------------- GEMM1 (C^T orientation) -----------------------------------
#define QSCALE 0.1803368801f
__global__ __launch_bounds__(256) void gemm_qkv(const u16* __restrict__ W,
                                                const u16* __restrict__ X,
                                                const float* __restrict__ bias,
                                                u16* __restrict__ Kg,
                                                u16* __restrict__ Qg,
                                                u16* __restrict__ Vg) {
  __shared__ __align__(16) u16 As[128 * 64];
  __shared__ __align__(16) u16 Bs[128 * 64];
  const int K = 1024;
  int lin = blockIdx.x;
  int xcd = lin & 7, idx = lin >> 3;
  int mb = (idx % 12) + 12 * (xcd & 1);
  int sb = (idx / 12) + 16 * (xcd >> 1);
  int m0 = mb * 128, n0 = sb * 128;
  f32x4 acc[4][4];
#pragma unroll
  for (int i = 0; i < 4; i++)
#pragma unroll
    for (int j = 0; j < 4; j++) acc[i][j] = (f32x4)0.0f;
  gemm_core_128(W, X, K, m0, n0, As, Bs, acc);

  int t = threadIdx.x, lane = t & 63, w = t >> 6;
  int quad = lane >> 4, l16 = lane & 15;
  int wm = (w >> 1) * 64, wn = (w & 1) * 64;
  int which = m0 >> 10;
#pragma unroll
  for (int tm = 0; tm < 4; tm++) {
    int nf0 = m0 + wm + tm * 16 + quad * 4;
    int h = (nf0 >> 6) & 15, d0 = nf0 & 63;
    f32x4 bv = *(const f32x4*)&bias[nf0];
#pragma unroll
    for (int tn = 0; tn < 4; tn++) {
      int s_abs = n0 + wn + tn * 16 + l16;
      int b = s_abs >> 11, s = s_abs & 2047;
      long bh = (long)b * 16 + h;
      f32x4 v;
#pragma unroll
      for (int r = 0; r < 4; r++) v[r] = acc[tm][tn][r] + bv[r];
      if (which == 0) {
        u32x2 pk;
        pk[0] = pk2bf(v[0], v[1]);
        pk[1] = pk2bf(v[2], v[3]);
        *(u32x2*)&Kg[(bh * 2048 + s) * 64 + d0] = pk;
      } else if (which == 1) {
        u32x2 pk;
        pk[0] = pk2bf(v[0] * QSCALE, v[1] * QSCALE);
        pk[1] = pk2bf(v[2] * QSCALE, v[3] * QSCALE);
        *(u32x2*)&Qg[(bh * 2048 + s) * 64 + d0] = pk;
      } else {
#pragma unroll
        for (int r = 0; r < 4; r++)
          Vg[(bh * 64 + d0 + r) * 2048 + s] = f2bf(v[r]);
      }
    }
  }
}

// ---------------- GEMM2 (C^T orientation) -----------------------------------
__global__ __launch_bounds__(256) void gemm_out(const u16* __restrict__ W,
                                                const u16* __restrict__ Y,
                                                const float* __restrict__ bias,
                                                float* __restrict__ out) {
  __shared__ __align__(16) u16 As[128 * 64];
  __shared__ __align__(16) u16 Bs[128 * 64];
  const int K = 1024;
  int lin = blockIdx.x;
  int xcd = lin & 7, idx = lin >> 3;
  int mb = idx & 7;
  int sb = (idx >> 3) + 8 * xcd;
  int m0 = mb * 128, n0 = sb * 128;
  f32x4 acc[4][4];
#pragma unroll
  for (int i = 0; i < 4; i++)
#pragma unroll
    for (int j = 0; j < 4; j++) acc[i][j] = (f32x4)0.0f;
  gemm_core_128(W, Y, K, m0, n0, As, Bs, acc);

  int t = threadIdx.x, lane = t & 63, w = t >> 6;
  int quad = lane >> 4, l16 = lane & 15;
  int wm = (w >> 1) * 64, wn = (w & 1) * 64;
#pragma unroll
  for (int tm = 0; tm < 4; tm++) {
    int nf0 = m0 + wm + tm * 16 + quad * 4;
    f32x4 bv = *(const f32x4*)&bias[nf0];
#pragma unroll
    for (int tn = 0; tn < 4; tn++) {
      int s_abs = n0 + wn + tn * 16 + l16;
      f32x4 o;
#pragma unroll
      for (int r = 0; r < 4; r++) o[r] = acc[tm][tn][r] + bv[r];
      *(f32x4*)&out[(long)s_abs * 1024 + nf0] = o;
    }
  }
}

// ---------------- flash attention: barrier-free kv-split waves --------------
// grid = 1024: block = (bh, 128 q). Wave (wq,wk): q-half wq*64, kv tiles
// t ≡ wk (mod 2). K/V frags loaded DIRECTLY global->register, register-
// double-buffered; only P transits LDS (per-wave region, no barriers in the
// main loop). End: barrier -> wk=1 publishes partials into reused Ps ->
// barrier -> wk=0 combines. (The pre-publish barrier is REQUIRED: Ps regions
// being repurposed belong to waves that may still be in their main loop.)
__device__ __forceinline__ void ld_kv(const u16* Kb, const u16* Vb, int kv0,
                                      int l16, int quad,
                                      bf16x8 kf[4][2], bf16x8 vf[4][2]) {
#pragma unroll
  for (int tn = 0; tn < 4; tn++) {
    const u16* kp = Kb + (long)(kv0 + tn * 16 + l16) * 64 + quad * 8;
    kf[tn][0] = *(const bf16x8*)kp;
    kf[tn][1] = *(const bf16x8*)(kp + 32);
    const u16* vp = Vb + (long)(tn * 16 + l16) * 2048 + kv0 + quad * 8;
    vf[tn][0] = *(const bf16x8*)vp;
    vf[tn][1] = *(const bf16x8*)(vp + 32);
  }
}

__device__ __forceinline__ void tile_compute(const bf16x8 kf[4][2],
                                             const bf16x8 vf[4][2],
                                             const bf16x8 qf[4][2], u16* Pw,
                                             int l16, int quad, int swz,
                                             float lsum[4], f32x4 acc[4][4]) {
#pragma unroll
  for (int tq = 0; tq < 4; tq++) {
    f32x4 s[4];
#pragma unroll
    for (int tn = 0; tn < 4; tn++) s[tn] = (f32x4)0.0f;
#pragma unroll
    for (int ks = 0; ks < 2; ks++)
#pragma unroll
      for (int tn = 0; tn < 4; tn++)
        s[tn] = __builtin_amdgcn_mfma_f32_16x16x32_bf16(kf[tn][ks], qf[tq][ks],
                                                        s[tn], 0, 0, 0);
    int qrow = tq * 16 + l16;
#pragma unroll
    for (int tn = 0; tn < 4; tn++) {
      float e0 = fexp2(s[tn][0]);
      float e1 = fexp2(s[tn][1]);
      float e2 = fexp2(s[tn][2]);
      float e3 = fexp2(s[tn][3]);
      lsum[tq] += (e0 + e1) + (e2 + e3);
      u32x2 pk;
      pk[0] = pk2bf(e0, e1);
      pk[1] = pk2bf(e2, e3);
      int c2 = ((tn * 2 + (quad >> 1)) ^ swz) * 2 + (quad & 1);
      *(u32x2*)&Pw[qrow * 64 + c2 * 4] = pk;
    }
  }
#pragma unroll
  for (int ks = 0; ks < 2; ks++) {
#pragma unroll
    for (int tq = 0; tq < 4; tq++) {
      bf16x8 pf = *(const bf16x8*)&Pw[(tq * 16 + l16) * 64 + ((ks * 4 + quad) ^ swz) * 8];
#pragma unroll
      for (int tn = 0; tn < 4; tn++)
        acc[tn][tq] = __builtin_amdgcn_mfma_f32_16x16x32_bf16(vf[tn][ks], pf,
                                                              acc[tn][tq], 0, 0, 0);
    }
  }
}

__global__ __launch_bounds__(256, 2) void attn_kernel(const u16* __restrict__ Qg,
                                                      const u16* __restrict__ Kg,
                                                      const u16* __restrict__ Vg,
                                                      u16* __restrict__ Y) {
  __shared__ __align__(16) u16 Ps[4 * 64 * 64];  // per-wave P; reused for combine
  __shared__ float Ls[2][64];                    // wk=1 lsum partials per q-half
  int t = threadIdx.x, lane = t & 63, w = t >> 6;
  int wq = w >> 1, wk = w & 1;
  int quad = lane >> 4, l16 = lane & 15;
  // XCD swizzle: all 16 q-chunks of a bh land on one XCD
  int lin = blockIdx.x;
  int bh = (lin & 7) + (lin >> 7) * 8;
  int qc = (lin >> 3) & 15;
  int q0 = qc * 128 + wq * 64;
  u16* Pw = Ps + w * 64 * 64;
  int swz = l16 & 7;

  const u16* Kbase = Kg + (long)bh * 2048 * 64;
  const u16* Vbase = Vg + (long)bh * 64 * 2048;

  // Q fragments (MFMA B-operand), loaded once
  bf16x8 qf[4][2];
#pragma unroll
  for (int tq = 0; tq < 4; tq++) {
    const u16* qp = Qg + ((long)bh * 2048 + q0 + tq * 16 + l16) * 64;
    qf[tq][0] = *(const bf16x8*)(qp + quad * 8);
    qf[tq][1] = *(const bf16x8*)(qp + 32 + quad * 8);
  }

  float lsum[4] = {0.0f, 0.0f, 0.0f, 0.0f};
  f32x4 acc[4][4];  // [tn d][tq q]  out^T
#pragma unroll
  for (int tn = 0; tn < 4; tn++)
#pragma unroll
    for (int tq = 0; tq < 4; tq++) acc[tn][tq] = (f32x4)0.0f;

  // 16 tiles per wave (kv ≡ wk mod 2), register-double-buffered, NO barriers
  bf16x8 kfa[4][2], vfa[4][2], kfb[4][2], vfb[4][2];
  ld_kv(Kbase, Vbase, wk * 64, l16, quad, kfa, vfa);
#pragma unroll 1
  for (int i = 0; i < 16; i += 2) {
    ld_kv(Kbase, Vbase, (i + 1) * 128 + wk * 64, l16, quad, kfb, vfb);
    tile_compute(kfa, vfa, qf, Pw, l16, quad, swz, lsum, acc);
    if (i + 2 < 16)
      ld_kv(Kbase, Vbase, (i + 2) * 128 + wk * 64, l16, quad, kfa, vfa);
    tile_compute(kfb, vfb, qf, Pw, l16, quad, swz, lsum, acc);
  }

  // in-wave cross-quad lsum reduce
#pragma unroll
  for (int tq = 0; tq < 4; tq++) {
    lsum[tq] += __shfl_xor(lsum[tq], 16, 64);
    lsum[tq] += __shfl_xor(lsum[tq], 32, 64);
  }

  // All waves must finish their main loop before Ps is repurposed (wk=1's
  // fb region overlaps wk=0's live P scratch) -- REQUIRED barrier.
  __syncthreads();

  // wk=1 waves publish partials into the (now-dead) P region: [q][d] fp32,
  // d-chunks XOR-swizzled by l16 for conflict-free b128.
  if (wk == 1) {
    float* fb = (float*)Ps + (w >> 1) * 4096;  // 16KB per q-half
#pragma unroll
    for (int tn = 0; tn < 4; tn++)
#pragma unroll
      for (int tq = 0; tq < 4; tq++)
        *(f32x4*)&fb[(tq * 16 + l16) * 64 + ((tn * 4 + quad) ^ l16) * 4] = acc[tn][tq];
    if (quad == 0)
#pragma unroll
      for (int tq = 0; tq < 4; tq++) Ls[wq][tq * 16 + l16] = lsum[tq];
  }
  __syncthreads();

  if (wk == 0) {
    const float* fb = (const float*)Ps + (w >> 1) * 4096;
#pragma unroll
    for (int tn = 0; tn < 4; tn++)
#pragma unroll
      for (int tq = 0; tq < 4; tq++) {
        f32x4 p = *(const f32x4*)&fb[(tq * 16 + l16) * 64 + ((tn * 4 + quad) ^ l16) * 4];
#pragma unroll
        for (int r = 0; r < 4; r++) acc[tn][tq][r] += p[r];
      }
    int b = bh >> 4, h = bh & 15;
#pragma unroll
    for (int tq = 0; tq < 4; tq++) {
      float inv = 1.0f / (lsum[tq] + Ls[wq][tq * 16 + l16]);
      long row = (long)b * 2048 + q0 + tq * 16 + l16;
#pragma unroll
      for (int tn = 0; tn < 4; tn++) {
        u32x2 pk;
        pk[0] = pk2bf(acc[tn][tq][0] * inv, acc[tn][tq][1] * inv);
        pk[1] = pk2bf(acc[tn][tq][2] * inv, acc[tn][tq][3] * inv);
        *(u32x2*)&Y[row * 1024 + h * 64 + tn * 16 + quad * 4] = pk;
      }
    }
  }
}

// ---------------- launch ----------------------------------------------------
extern "C" void kernel_launch(void* const* d_in, const int* in_sizes, int n_in,
                              void* d_out, int out_size, void* d_ws, size_t ws_size,
                              hipStream_t stream) {
  const float* x = (const float*)d_in[0];       // (4,2048,1024)
  const float* W_attn = (const float*)d_in[1];  // (3072,1024)
  const float* b_attn = (const float*)d_in[2];  // (3072,)
  const float* W_out = (const float*)d_in[3];   // (1024,1024)
  const float* b_out = (const float*)d_in[4];   // (1024,)
  float* out = (float*)d_out;                   // (4,2048,1024) fp32

  char* ws = (char*)d_ws;
  u16* xb = (u16*)ws;                             // 16 MB
  u16* Wab = (u16*)(ws + 16777216);               // 6 MB
  u16* Wob = (u16*)(ws + 16777216 + 6291456);     // 2 MB
  u16* Kg = (u16*)(ws + 25165824);                // (b,h,s,d) 16 MB
  u16* Qg = Kg + 8388608;                         // (b,h,s,d) pre-scaled 16 MB
  u16* Vg = Qg + 8388608;                         // (b,h,d,s) 16 MB
  u16* Yb = xb;  // alias: x dead after GEMM1

  cvt_f32_bf16<<<4096, 256, 0, stream>>>(x, xb);
  cvt_f32_bf16<<<1536, 256, 0, stream>>>(W_attn, Wab);
  cvt_f32_bf16<<<512, 256, 0, stream>>>(W_out, Wob);

  gemm_qkv<<<1536, 256, 0, stream>>>(Wab, xb, b_attn, Kg, Qg, Vg);
  attn_kernel<<<1024, 256, 0, stream>>>(Qg, Kg, Vg, Yb);
  gemm_out<<<512, 256, 0, stream>>>(Wob, Yb, b_out, out);
}

// Round 9
// 321.070 us; speedup vs baseline: 1.3326x; 1.3326x over previous
//
#include <hip/hip_runtime.h>

typedef unsigned short u16;
typedef unsigned int u32;
typedef __attribute__((ext_vector_type(2))) u32 u32x2;
typedef __attribute__((ext_vector_type(4))) u32 u32x4;
typedef __attribute__((ext_vector_type(8))) short bf16x8;
typedef __attribute__((ext_vector_type(4))) float f32x4;

// round-to-nearest-even fp32 -> bf16 (scalar fallback)
__device__ __forceinline__ u16 f2bf(float f) {
  u32 b = __float_as_uint(f);
  b += 0x7fffu + ((b >> 16) & 1u);
  return (u16)(b >> 16);
}

// packed fp32x2 -> bf16x2
__device__ __forceinline__ u32 pk2bf(float a, float b) {
#if __has_builtin(__builtin_amdgcn_cvt_pk_bf16_f32)
  return __builtin_bit_cast(u32, __builtin_amdgcn_cvt_pk_bf16_f32(a, b));
#else
  return (u32)f2bf(a) | ((u32)f2bf(b) << 16);
#endif
}

// 2^x via native v_exp_f32 (NOTE: __exp2f is a reserved glibc symbol)
__device__ __forceinline__ float fexp2(float x) {
#if __has_builtin(__builtin_amdgcn_exp2f)
  return __builtin_amdgcn_exp2f(x);
#else
  return exp2f(x);
#endif
}

// async global->LDS, 16B/lane (GEMM cores only)
__device__ __forceinline__ void gload_lds16(const u16* g, u16* l) {
  __builtin_amdgcn_global_load_lds((const __attribute__((address_space(1))) void*)g,
                                   (__attribute__((address_space(3))) void*)l, 16, 0, 0);
}

// ---------------- fp32 -> bf16 convert, 8 elems/thread ----------------------
__global__ __launch_bounds__(256) void cvt_f32_bf16(const float* __restrict__ in,
                                                    u16* __restrict__ out) {
  long i = ((long)blockIdx.x * 256 + threadIdx.x) * 8;
  u32 u[8];
#pragma unroll
  for (int j = 0; j < 8; j++) {
    u32 b = __float_as_uint(in[i + j]);
    u[j] = (b + 0x7fffu + ((b >> 16) & 1u)) >> 16;
  }
  u32x4 o;
  o[0] = u[0] | (u[1] << 16);
  o[1] = u[2] | (u[3] << 16);
  o[2] = u[4] | (u[5] << 16);
  o[3] = u[6] | (u[7] << 16);
  *(u32x4*)(out + i) = o;
}

// ---------------- shared GEMM core: C[128x128] = A[128xK] * B[128xK]^T ------
__device__ __forceinline__ void gemm_core_128(const u16* __restrict__ A,
                                              const u16* __restrict__ B, int K,
                                              int m0, int n0, u16* As, u16* Bs,
                                              f32x4 acc[4][4]) {
  int t = threadIdx.x;
  int lane = t & 63, w = t >> 6;
  int quad = lane >> 4, l16 = lane & 15;
  int wm = (w >> 1) * 64, wn = (w & 1) * 64;
  int lr = lane >> 3, lc = lane & 7;
  int cg = lc ^ lr;
  int swz = l16 & 7;
  for (int k0 = 0; k0 < K; k0 += 64) {
#pragma unroll
    for (int i = 0; i < 4; i++) {
      int r0 = i * 32 + w * 8;
      gload_lds16(&A[(long)(m0 + r0 + lr) * K + k0 + cg * 8], &As[r0 * 64]);
      gload_lds16(&B[(long)(n0 + r0 + lr) * K + k0 + cg * 8], &Bs[r0 * 64]);
    }
    __syncthreads();
#pragma unroll
    for (int ks = 0; ks < 2; ks++) {
      bf16x8 a[4], b[4];
#pragma unroll
      for (int tm = 0; tm < 4; tm++)
        a[tm] = *(const bf16x8*)&As[(wm + tm * 16 + l16) * 64 + ((ks * 4 + quad) ^ swz) * 8];
#pragma unroll
      for (int tn = 0; tn < 4; tn++)
        b[tn] = *(const bf16x8*)&Bs[(wn + tn * 16 + l16) * 64 + ((ks * 4 + quad) ^ swz) * 8];
#pragma unroll
      for (int tm = 0; tm < 4; tm++)
#pragma unroll
        for (int tn = 0; tn < 4; tn++)
          acc[tm][tn] = __builtin_amdgcn_mfma_f32_16x16x32_bf16(a[tm], b[tn],
                                                                acc[tm][tn], 0, 0, 0);
    }
    __syncthreads();
  }
}

// ---------------- GEMM1 (C^T orientation) -----------------------------------
#define QSCALE 0.1803368801f
__global__ __launch_bounds__(256) void gemm_qkv(const u16* __restrict__ W,
                                                const u16* __restrict__ X,
                                                const float* __restrict__ bias,
                                                u16* __restrict__ Kg,
                                                u16* __restrict__ Qg,
                                                u16* __restrict__ Vg) {
  __shared__ __align__(16) u16 As[128 * 64];
  __shared__ __align__(16) u16 Bs[128 * 64];
  const int K = 1024;
  int lin = blockIdx.x;
  int xcd = lin & 7, idx = lin >> 3;
  int mb = (idx % 12) + 12 * (xcd & 1);
  int sb = (idx / 12) + 16 * (xcd >> 1);
  int m0 = mb * 128, n0 = sb * 128;
  f32x4 acc[4][4];
#pragma unroll
  for (int i = 0; i < 4; i++)
#pragma unroll
    for (int j = 0; j < 4; j++) acc[i][j] = (f32x4)0.0f;
  gemm_core_128(W, X, K, m0, n0, As, Bs, acc);

  int t = threadIdx.x, lane = t & 63, w = t >> 6;
  int quad = lane >> 4, l16 = lane & 15;
  int wm = (w >> 1) * 64, wn = (w & 1) * 64;
  int which = m0 >> 10;
#pragma unroll
  for (int tm = 0; tm < 4; tm++) {
    int nf0 = m0 + wm + tm * 16 + quad * 4;
    int h = (nf0 >> 6) & 15, d0 = nf0 & 63;
    f32x4 bv = *(const f32x4*)&bias[nf0];
#pragma unroll
    for (int tn = 0; tn < 4; tn++) {
      int s_abs = n0 + wn + tn * 16 + l16;
      int b = s_abs >> 11, s = s_abs & 2047;
      long bh = (long)b * 16 + h;
      f32x4 v;
#pragma unroll
      for (int r = 0; r < 4; r++) v[r] = acc[tm][tn][r] + bv[r];
      if (which == 0) {
        u32x2 pk;
        pk[0] = pk2bf(v[0], v[1]);
        pk[1] = pk2bf(v[2], v[3]);
        *(u32x2*)&Kg[(bh * 2048 + s) * 64 + d0] = pk;
      } else if (which == 1) {
        u32x2 pk;
        pk[0] = pk2bf(v[0] * QSCALE, v[1] * QSCALE);
        pk[1] = pk2bf(v[2] * QSCALE, v[3] * QSCALE);
        *(u32x2*)&Qg[(bh * 2048 + s) * 64 + d0] = pk;
      } else {
#pragma unroll
        for (int r = 0; r < 4; r++)
          Vg[(bh * 64 + d0 + r) * 2048 + s] = f2bf(v[r]);
      }
    }
  }
}

// ---------------- GEMM2 (C^T orientation) -----------------------------------
__global__ __launch_bounds__(256) void gemm_out(const u16* __restrict__ W,
                                                const u16* __restrict__ Y,
                                                const float* __restrict__ bias,
                                                float* __restrict__ out) {
  __shared__ __align__(16) u16 As[128 * 64];
  __shared__ __align__(16) u16 Bs[128 * 64];
  const int K = 1024;
  int lin = blockIdx.x;
  int xcd = lin & 7, idx = lin >> 3;
  int mb = idx & 7;
  int sb = (idx >> 3) + 8 * xcd;
  int m0 = mb * 128, n0 = sb * 128;
  f32x4 acc[4][4];
#pragma unroll
  for (int i = 0; i < 4; i++)
#pragma unroll
    for (int j = 0; j < 4; j++) acc[i][j] = (f32x4)0.0f;
  gemm_core_128(W, Y, K, m0, n0, As, Bs, acc);

  int t = threadIdx.x, lane = t & 63, w = t >> 6;
  int quad = lane >> 4, l16 = lane & 15;
  int wm = (w >> 1) * 64, wn = (w & 1) * 64;
#pragma unroll
  for (int tm = 0; tm < 4; tm++) {
    int nf0 = m0 + wm + tm * 16 + quad * 4;
    f32x4 bv = *(const f32x4*)&bias[nf0];
#pragma unroll
    for (int tn = 0; tn < 4; tn++) {
      int s_abs = n0 + wn + tn * 16 + l16;
      f32x4 o;
#pragma unroll
      for (int r = 0; r < 4; r++) o[r] = acc[tm][tn][r] + bv[r];
      *(f32x4*)&out[(long)s_abs * 1024 + nf0] = o;
    }
  }
}

// ---------------- flash attention: barrier-free, register-budgeted ----------
// grid = 1024: block = (bh, 128 q). Wave (wq,wk): q-half wq*64, kv tiles
// t ≡ wk (mod 2). NO barriers in the main loop; P in per-wave LDS.
// Register budget (fits __launch_bounds__(256,2) 128-arch + 128-acc cap):
//   qf 32 + vf 32 (held per tile) + kf 8 (streamed per 16-kv subtile)
//   + s 16 + addr/misc ~25 = ~113 arch; acc 64 in AGPRs.  NO SPILL.
__global__ __launch_bounds__(256, 2) void attn_kernel(const u16* __restrict__ Qg,
                                                      const u16* __restrict__ Kg,
                                                      const u16* __restrict__ Vg,
                                                      u16* __restrict__ Y) {
  __shared__ __align__(16) u16 Ps[4 * 64 * 64];  // per-wave P; reused for combine
  __shared__ float Ls[2][64];                    // wk=1 lsum partials per q-half
  int t = threadIdx.x, lane = t & 63, w = t >> 6;
  int wq = w >> 1, wk = w & 1;
  int quad = lane >> 4, l16 = lane & 15;
  // XCD swizzle: all 16 q-chunks of a bh land on one XCD
  int lin = blockIdx.x;
  int bh = (lin & 7) + (lin >> 7) * 8;
  int qc = (lin >> 3) & 15;
  int q0 = qc * 128 + wq * 64;
  u16* Pw = Ps + w * 64 * 64;
  int swz = l16 & 7;

  const u16* Kbase = Kg + (long)bh * 2048 * 64;
  const u16* Vbase = Vg + (long)bh * 64 * 2048;

  // Q fragments (MFMA B-operand), loaded once
  bf16x8 qf[4][2];
#pragma unroll
  for (int tq = 0; tq < 4; tq++) {
    const u16* qp = Qg + ((long)bh * 2048 + q0 + tq * 16 + l16) * 64;
    qf[tq][0] = *(const bf16x8*)(qp + quad * 8);
    qf[tq][1] = *(const bf16x8*)(qp + 32 + quad * 8);
  }

  float lsum[4] = {0.0f, 0.0f, 0.0f, 0.0f};
  f32x4 acc[4][4];  // [tn d][tq q]  out^T
#pragma unroll
  for (int tn = 0; tn < 4; tn++)
#pragma unroll
    for (int tq = 0; tq < 4; tq++) acc[tn][tq] = (f32x4)0.0f;

#pragma unroll 1
  for (int tile = 0; tile < 16; tile++) {
    int kv0 = tile * 128 + wk * 64;
    // V fragments for this tile: issued FIRST (independent of QK^T), held.
    bf16x8 vf[4][2];
#pragma unroll
    for (int tn = 0; tn < 4; tn++) {
      const u16* vp = Vbase + (long)(tn * 16 + l16) * 2048 + kv0 + quad * 8;
      vf[tn][0] = *(const bf16x8*)vp;
      vf[tn][1] = *(const bf16x8*)(vp + 32);
    }
    // QK^T streamed per 16-kv subtile: only one kf pair live at a time.
#pragma unroll
    for (int tn = 0; tn < 4; tn++) {
      const u16* kp = Kbase + (long)(kv0 + tn * 16 + l16) * 64 + quad * 8;
      bf16x8 kf0 = *(const bf16x8*)kp;
      bf16x8 kf1 = *(const bf16x8*)(kp + 32);
      f32x4 s[4];
#pragma unroll
      for (int tq = 0; tq < 4; tq++) {
        s[tq] = __builtin_amdgcn_mfma_f32_16x16x32_bf16(kf0, qf[tq][0],
                                                        (f32x4)0.0f, 0, 0, 0);
        s[tq] = __builtin_amdgcn_mfma_f32_16x16x32_bf16(kf1, qf[tq][1], s[tq], 0, 0, 0);
      }
#pragma unroll
      for (int tq = 0; tq < 4; tq++) {
        float e0 = fexp2(s[tq][0]);
        float e1 = fexp2(s[tq][1]);
        float e2 = fexp2(s[tq][2]);
        float e3 = fexp2(s[tq][3]);
        lsum[tq] += (e0 + e1) + (e2 + e3);
        u32x2 pk;
        pk[0] = pk2bf(e0, e1);
        pk[1] = pk2bf(e2, e3);
        int c2 = ((tn * 2 + (quad >> 1)) ^ swz) * 2 + (quad & 1);
        *(u32x2*)&Pw[(tq * 16 + l16) * 64 + c2 * 4] = pk;
      }
    }
    // PV: out^T += V^T · P^T (P from per-wave LDS; same-wave dep, no barrier)
#pragma unroll
    for (int ks = 0; ks < 2; ks++) {
#pragma unroll
      for (int tq = 0; tq < 4; tq++) {
        bf16x8 pf = *(const bf16x8*)&Pw[(tq * 16 + l16) * 64 + ((ks * 4 + quad) ^ swz) * 8];
#pragma unroll
        for (int tn = 0; tn < 4; tn++)
          acc[tn][tq] = __builtin_amdgcn_mfma_f32_16x16x32_bf16(vf[tn][ks], pf,
                                                                acc[tn][tq], 0, 0, 0);
      }
    }
  }

  // in-wave cross-quad lsum reduce
#pragma unroll
  for (int tq = 0; tq < 4; tq++) {
    lsum[tq] += __shfl_xor(lsum[tq], 16, 64);
    lsum[tq] += __shfl_xor(lsum[tq], 32, 64);
  }

  // All waves must finish their main loop before Ps is repurposed (wk=1's
  // fb region overlaps wk=0's live P scratch) -- REQUIRED barrier.
  __syncthreads();

  // wk=1 waves publish partials: [q][d] fp32, d-chunks XOR-swizzled by l16.
  if (wk == 1) {
    float* fb = (float*)Ps + (w >> 1) * 4096;  // 16KB per q-half
#pragma unroll
    for (int tn = 0; tn < 4; tn++)
#pragma unroll
      for (int tq = 0; tq < 4; tq++)
        *(f32x4*)&fb[(tq * 16 + l16) * 64 + ((tn * 4 + quad) ^ l16) * 4] = acc[tn][tq];
    if (quad == 0)
#pragma unroll
      for (int tq = 0; tq < 4; tq++) Ls[wq][tq * 16 + l16] = lsum[tq];
  }
  __syncthreads();

  if (wk == 0) {
    const float* fb = (const float*)Ps + (w >> 1) * 4096;
#pragma unroll
    for (int tn = 0; tn < 4; tn++)
#pragma unroll
      for (int tq = 0; tq < 4; tq++) {
        f32x4 p = *(const f32x4*)&fb[(tq * 16 + l16) * 64 + ((tn * 4 + quad) ^ l16) * 4];
#pragma unroll
        for (int r = 0; r < 4; r++) acc[tn][tq][r] += p[r];
      }
    int b = bh >> 4, h = bh & 15;
#pragma unroll
    for (int tq = 0; tq < 4; tq++) {
      float inv = 1.0f / (lsum[tq] + Ls[wq][tq * 16 + l16]);
      long row = (long)b * 2048 + q0 + tq * 16 + l16;
#pragma unroll
      for (int tn = 0; tn < 4; tn++) {
        u32x2 pk;
        pk[0] = pk2bf(acc[tn][tq][0] * inv, acc[tn][tq][1] * inv);
        pk[1] = pk2bf(acc[tn][tq][2] * inv, acc[tn][tq][3] * inv);
        *(u32x2*)&Y[row * 1024 + h * 64 + tn * 16 + quad * 4] = pk;
      }
    }
  }
}

// ---------------- launch ----------------------------------------------------
extern "C" void kernel_launch(void* const* d_in, const int* in_sizes, int n_in,
                              void* d_out, int out_size, void* d_ws, size_t ws_size,
                              hipStream_t stream) {
  const float* x = (const float*)d_in[0];       // (4,2048,1024)
  const float* W_attn = (const float*)d_in[1];  // (3072,1024)
  const float* b_attn = (const float*)d_in[2];  // (3072,)
  const float* W_out = (const float*)d_in[3];   // (1024,1024)
  const float* b_out = (const float*)d_in[4];   // (1024,)
  float* out = (float*)d_out;                   // (4,2048,1024) fp32

  char* ws = (char*)d_ws;
  u16* xb = (u16*)ws;                             // 16 MB
  u16* Wab = (u16*)(ws + 16777216);               // 6 MB
  u16* Wob = (u16*)(ws + 16777216 + 6291456);     // 2 MB
  u16* Kg = (u16*)(ws + 25165824);                // (b,h,s,d) 16 MB
  u16* Qg = Kg + 8388608;                         // (b,h,s,d) pre-scaled 16 MB
  u16* Vg = Qg + 8388608;                         // (b,h,d,s) 16 MB
  u16* Yb = xb;  // alias: x dead after GEMM1

  cvt_f32_bf16<<<4096, 256, 0, stream>>>(x, xb);
  cvt_f32_bf16<<<1536, 256, 0, stream>>>(W_attn, Wab);
  cvt_f32_bf16<<<512, 256, 0, stream>>>(W_out, Wob);

  gemm_qkv<<<1536, 256, 0, stream>>>(Wab, xb, b_attn, Kg, Qg, Vg);
  attn_kernel<<<1024, 256, 0, stream>>>(Qg, Kg, Vg, Yb);
  gemm_out<<<512, 256, 0, stream>>>(Wob, Yb, b_out, out);
}